// Round 1
// baseline (441.597 us; speedup 1.0000x reference)
//
#include <hip/hip_runtime.h>
#include <hip/hip_bf16.h>

using bf16 = __hip_bfloat16;
typedef __attribute__((ext_vector_type(4))) float f32x4;
typedef short s16x8 __attribute__((ext_vector_type(8)));
typedef unsigned short u16x8 __attribute__((ext_vector_type(8)));

__device__ __forceinline__ unsigned short f2b(float f) {
  bf16 h = __float2bfloat16(f);
  return __builtin_bit_cast(unsigned short, h);
}
__device__ __forceinline__ float b2f(unsigned short u) {
  bf16 h = __builtin_bit_cast(bf16, u);
  return __bfloat162float(h);
}

__device__ __forceinline__ void async_copy16(const void* g, void* lds) {
  __builtin_amdgcn_global_load_lds(
      (const __attribute__((address_space(1))) void*)g,
      (__attribute__((address_space(3))) void*)lds, 16, 0, 0);
}

// ---------------- fp32 -> bf16 convert (8 elems/thread) ----------------
__global__ __launch_bounds__(256) void cvt_f32_to_bf16(const float* __restrict__ in,
                                                       ushort* __restrict__ out) {
  long i = ((long)blockIdx.x * 256 + threadIdx.x) * 8;
  float4 a = *(const float4*)(in + i);
  float4 b = *(const float4*)(in + i + 4);
  u16x8 o;
  o[0] = f2b(a.x); o[1] = f2b(a.y); o[2] = f2b(a.z); o[3] = f2b(a.w);
  o[4] = f2b(b.x); o[5] = f2b(b.y); o[6] = f2b(b.z); o[7] = f2b(b.w);
  *(u16x8*)(out + i) = o;
}

// ---------------- RoPE in-place on q,k halves of qkv buffer ----------------
// qkv: [8192][3072] bf16; f = which*1024 + h*64 + d
__global__ __launch_bounds__(256) void rope_kernel(ushort* __restrict__ qkv,
                                                   const float* __restrict__ cosT,
                                                   const float* __restrict__ sinT) {
  long idx = (long)blockIdx.x * 256 + threadIdx.x;  // 8388608 total
  int d = idx & 31;
  int h = (int)((idx >> 5) & 15);
  int which = (int)((idx >> 9) & 1);
  long row = idx >> 10;
  int s = (int)(row & 2047);
  long base = row * 3072 + which * 1024 + h * 64;
  float lo = b2f(qkv[base + d]);
  float hi = b2f(qkv[base + d + 32]);
  float c0 = cosT[s * 64 + d], s0 = sinT[s * 64 + d];
  float c1 = cosT[s * 64 + d + 32], s1 = sinT[s * 64 + d + 32];
  qkv[base + d]      = f2b(lo * c0 - hi * s0);
  qkv[base + d + 32] = f2b(hi * c1 + lo * s1);
}

// ---------------- bf16 GEMM: C[M][N] = A[M][K] * B[N][K]^T ----------------
// m97 structure: 128x128 tile, BK=64, 4 waves (2x2), 16x16x32 MFMA,
// global_load_lds width-16 staging.
__device__ __forceinline__ void storeC(float* p, float v) { *p = v; }
__device__ __forceinline__ void storeC(bf16* p, float v) { *p = __float2bfloat16(v); }

template <typename CT>
__global__ __launch_bounds__(256) void gemm_bt(const bf16* __restrict__ A,
                                               const bf16* __restrict__ B,
                                               CT* __restrict__ C,
                                               int M, int N, int K) {
  __shared__ bf16 As[128 * 64];
  __shared__ bf16 Bs[128 * 64];
  const int tid = threadIdx.x;
  const int lane = tid & 63;
  const int wid = tid >> 6;
  const int tm = blockIdx.y * 128;
  const int tn = blockIdx.x * 128;
  const int wr = wid >> 1, wc = wid & 1;
  const int srow = tid >> 3;         // 0..31
  const int scol = (tid & 7) * 8;    // 0..56

  f32x4 acc[4][4] = {};

  const bf16* Abase = A + (long)(tm + srow) * K + scol;
  const bf16* Bbase = B + (long)(tn + srow) * K + scol;

  const int lr = lane & 15;
  const int lk = (lane >> 4) * 8;

  for (int k0 = 0; k0 < K; k0 += 64) {
#pragma unroll
    for (int i = 0; i < 4; ++i) {
      async_copy16(Abase + (long)i * 32 * K + k0, (char*)As + wid * 1024 + i * 4096);
      async_copy16(Bbase + (long)i * 32 * K + k0, (char*)Bs + wid * 1024 + i * 4096);
    }
    __syncthreads();
#pragma unroll
    for (int ks = 0; ks < 2; ++ks) {
      s16x8 af[4], bff[4];
#pragma unroll
      for (int m = 0; m < 4; ++m)
        af[m] = *(const s16x8*)&As[(wr * 64 + m * 16 + lr) * 64 + ks * 32 + lk];
#pragma unroll
      for (int n = 0; n < 4; ++n)
        bff[n] = *(const s16x8*)&Bs[(wc * 64 + n * 16 + lr) * 64 + ks * 32 + lk];
#pragma unroll
      for (int m = 0; m < 4; ++m)
#pragma unroll
        for (int n = 0; n < 4; ++n)
          acc[m][n] = __builtin_amdgcn_mfma_f32_16x16x32_bf16(af[m], bff[n], acc[m][n], 0, 0, 0);
    }
    __syncthreads();
  }

  const int cc = lane & 15;
  const int cr = (lane >> 4) * 4;
#pragma unroll
  for (int m = 0; m < 4; ++m)
#pragma unroll
    for (int n = 0; n < 4; ++n) {
      long row0 = tm + wr * 64 + m * 16 + cr;
      long col = tn + wc * 64 + n * 16 + cc;
#pragma unroll
      for (int r = 0; r < 4; ++r)
        storeC(&C[(row0 + r) * (long)N + col], acc[m][n][r]);
    }
}

// ---------------- flash attention ----------------
// grid: (16 q-tiles, 64 (b,h) pairs), 256 threads = 4 waves, 32 q-rows/wave.
__global__ __launch_bounds__(256) void attn_kernel(const bf16* __restrict__ qkv,
                                                   ushort* __restrict__ o) {
  const int pair = blockIdx.y;
  const int b = pair >> 4, h = pair & 15;
  const int q0 = blockIdx.x * 128;
  const int tid = threadIdx.x, lane = tid & 63, wid = tid >> 6;

  const bf16* Qb = qkv + (long)b * 2048 * 3072 + h * 64;
  const bf16* Kb = Qb + 1024;
  const bf16* Vb = Qb + 2048;

  __shared__ bf16 Ks[64 * 64];
  __shared__ bf16 Vt[64 * 64];
  __shared__ bf16 Ps[4][32 * 72];

  const int lr = lane & 15;
  const int lk = (lane >> 4) * 8;

  // Q fragments held in registers for the whole kernel
  s16x8 qa[2][2];
#pragma unroll
  for (int m = 0; m < 2; ++m)
#pragma unroll
    for (int ks = 0; ks < 2; ++ks)
      qa[m][ks] = *(const s16x8*)(Qb + (long)(q0 + wid * 32 + m * 16 + lr) * 3072 + ks * 32 + lk);

  f32x4 oacc[2][4] = {};
  float mrow[2][4], lrow[2][4];
#pragma unroll
  for (int m = 0; m < 2; ++m)
#pragma unroll
    for (int r = 0; r < 4; ++r) { mrow[m][r] = -__builtin_inff(); lrow[m][r] = 0.f; }

  const float scale = 0.125f;

  for (int kt = 0; kt < 32; ++kt) {
    __syncthreads();
    // stage K tile [64 keys][64 d] with XOR-swizzled SOURCE columns (T2 via m173)
#pragma unroll
    for (int i = 0; i < 2; ++i) {
      int c = tid + i * 256;        // chunk 0..511
      int row = c >> 3;             // key row 0..63
      int colb = (c & 7) * 16;      // byte col in row
      int scolb = colb ^ ((row & 7) << 4);
      async_copy16(Kb + (long)(kt * 64 + row) * 3072 + (scolb >> 1),
                   (char*)Ks + wid * 1024 + i * 4096);
    }
    // stage V transposed (Vt[d][key]) + XOR swizzle, via registers
#pragma unroll
    for (int i = 0; i < 4; ++i) {
      int s0 = wid * 4 + i * 16;
      const bf16* vg = Vb + (long)(kt * 64 + s0) * 3072 + lane;
      ushort4 vv;
      vv.x = *(const ushort*)(vg);
      vv.y = *(const ushort*)(vg + 3072);
      vv.z = *(const ushort*)(vg + 2 * 3072);
      vv.w = *(const ushort*)(vg + 3 * 3072);
      int byte = lane * 128 + ((s0 * 2) ^ ((lane & 7) << 4));
      *(ushort4*)((char*)Vt + byte) = vv;
    }
    __syncthreads();

    // S = Q K^T  (per wave: 32 q-rows x 64 keys)
    f32x4 sacc[2][4] = {};
#pragma unroll
    for (int ks = 0; ks < 2; ++ks) {
      s16x8 kf[4];
#pragma unroll
      for (int n = 0; n < 4; ++n) {
        int row = n * 16 + lr;
        int colb = (ks * 32 + lk) * 2;
        kf[n] = *(const s16x8*)((const char*)Ks + row * 128 + (colb ^ ((row & 7) << 4)));
      }
#pragma unroll
      for (int m = 0; m < 2; ++m)
#pragma unroll
        for (int n = 0; n < 4; ++n)
          sacc[m][n] = __builtin_amdgcn_mfma_f32_16x16x32_bf16(qa[m][ks], kf[n], sacc[m][n], 0, 0, 0);
    }

    // online softmax (all 64 lanes active; reduce across 16-lane col groups)
#pragma unroll
    for (int m = 0; m < 2; ++m) {
#pragma unroll
      for (int r = 0; r < 4; ++r) {
        float v0 = sacc[m][0][r] * scale, v1 = sacc[m][1][r] * scale;
        float v2 = sacc[m][2][r] * scale, v3 = sacc[m][3][r] * scale;
        float tmax = fmaxf(fmaxf(v0, v1), fmaxf(v2, v3));
#pragma unroll
        for (int off = 1; off <= 8; off <<= 1)
          tmax = fmaxf(tmax, __shfl_xor(tmax, off, 64));
        float mold = mrow[m][r];
        float mnew = fmaxf(mold, tmax);
        float alpha = __expf(mold - mnew);
        float p0 = __expf(v0 - mnew), p1 = __expf(v1 - mnew);
        float p2 = __expf(v2 - mnew), p3 = __expf(v3 - mnew);
        float psum = p0 + p1 + p2 + p3;
#pragma unroll
        for (int off = 1; off <= 8; off <<= 1)
          psum += __shfl_xor(psum, off, 64);
        mrow[m][r] = mnew;
        lrow[m][r] = lrow[m][r] * alpha + psum;
        sacc[m][0][r] = p0; sacc[m][1][r] = p1; sacc[m][2][r] = p2; sacc[m][3][r] = p3;
#pragma unroll
        for (int n = 0; n < 4; ++n) oacc[m][n][r] *= alpha;
      }
    }

    // P (C-layout) -> LDS bf16 (padded stride 72 keeps 16B-aligned rows, ~2-way banks)
#pragma unroll
    for (int m = 0; m < 2; ++m)
#pragma unroll
      for (int n = 0; n < 4; ++n)
#pragma unroll
        for (int r = 0; r < 4; ++r) {
          int rl = (lane >> 4) * 4 + r;
          Ps[wid][(m * 16 + rl) * 72 + n * 16 + lr] = __float2bfloat16(sacc[m][n][r]);
        }

    // O += P V
#pragma unroll
    for (int ks = 0; ks < 2; ++ks) {
      s16x8 pa[2], vf[4];
#pragma unroll
      for (int m = 0; m < 2; ++m)
        pa[m] = *(const s16x8*)&Ps[wid][(m * 16 + lr) * 72 + ks * 32 + lk];
#pragma unroll
      for (int n = 0; n < 4; ++n) {
        int row = n * 16 + lr;
        int colb = (ks * 32 + lk) * 2;
        vf[n] = *(const s16x8*)((const char*)Vt + row * 128 + (colb ^ ((row & 7) << 4)));
      }
#pragma unroll
      for (int m = 0; m < 2; ++m)
#pragma unroll
        for (int n = 0; n < 4; ++n)
          oacc[m][n] = __builtin_amdgcn_mfma_f32_16x16x32_bf16(pa[m], vf[n], oacc[m][n], 0, 0, 0);
    }
  }

  // epilogue: O/l  -> o_flat[b*2048+s][h*64+d] (bf16)
#pragma unroll
  for (int m = 0; m < 2; ++m)
#pragma unroll
    for (int n = 0; n < 4; ++n)
#pragma unroll
      for (int r = 0; r < 4; ++r) {
        int rl = (lane >> 4) * 4 + r;
        long srow = q0 + wid * 32 + m * 16 + rl;
        int d = n * 16 + lr;
        float val = oacc[m][n][r] / lrow[m][r];
        o[((long)b * 2048 + srow) * 1024 + h * 64 + d] = f2b(val);
      }
}

// ---------------- launch ----------------
extern "C" void kernel_launch(void* const* d_in, const int* in_sizes, int n_in,
                              void* d_out, int out_size, void* d_ws, size_t ws_size,
                              hipStream_t stream) {
  const float* x    = (const float*)d_in[0];
  const float* cosT = (const float*)d_in[1];
  const float* sinT = (const float*)d_in[2];
  const float* Wqkv = (const float*)d_in[3];
  const float* Wout = (const float*)d_in[4];
  float* out = (float*)d_out;

  char* p = (char*)d_ws;
  bf16* xb    = (bf16*)p; p += (size_t)8192 * 1024 * 2;   // 16.8 MB
  bf16* wqkvb = (bf16*)p; p += (size_t)3072 * 1024 * 2;   //  6.3 MB
  bf16* woutb = (bf16*)p; p += (size_t)1024 * 1024 * 2;   //  2.1 MB
  bf16* qkvb  = (bf16*)p; p += (size_t)8192 * 3072 * 2;   // 50.3 MB
  bf16* ob    = (bf16*)p;                                 // 16.8 MB

  cvt_f32_to_bf16<<<4096, 256, 0, stream>>>(x, (ushort*)xb);
  cvt_f32_to_bf16<<<1536, 256, 0, stream>>>(Wqkv, (ushort*)wqkvb);
  cvt_f32_to_bf16<<<512, 256, 0, stream>>>(Wout, (ushort*)woutb);

  // qkv = x @ Wqkv^T : M=8192, N=3072, K=1024
  gemm_bt<bf16><<<dim3(24, 64), 256, 0, stream>>>(xb, wqkvb, qkvb, 8192, 3072, 1024);

  rope_kernel<<<32768, 256, 0, stream>>>((ushort*)qkvb, cosT, sinT);

  attn_kernel<<<dim3(16, 64), 256, 0, stream>>>(qkvb, (ushort*)ob);

  // out = o @ Wout^T : M=8192, N=1024, K=1024 (fp32 out)
  gemm_bt<float><<<dim3(8, 64), 256, 0, stream>>>(ob, woutb, out, 8192, 1024, 1024);
}

// Round 2
// 264.036 us; speedup vs baseline: 1.6725x; 1.6725x over previous
//
#include <hip/hip_runtime.h>
#include <hip/hip_bf16.h>

using bf16 = __hip_bfloat16;
typedef __attribute__((ext_vector_type(4))) float f32x4;
typedef short s16x8 __attribute__((ext_vector_type(8)));
typedef unsigned short u16x8 __attribute__((ext_vector_type(8)));

__device__ __forceinline__ unsigned short f2b(float f) {
  bf16 h = __float2bfloat16(f);
  return __builtin_bit_cast(unsigned short, h);
}
__device__ __forceinline__ float b2f(unsigned short u) {
  bf16 h = __builtin_bit_cast(bf16, u);
  return __bfloat162float(h);
}

__device__ __forceinline__ void async_copy16(const void* g, void* lds) {
  __builtin_amdgcn_global_load_lds(
      (const __attribute__((address_space(1))) void*)g,
      (__attribute__((address_space(3))) void*)lds, 16, 0, 0);
}

// ---------------- fp32 -> bf16 convert (8 elems/thread) ----------------
__global__ __launch_bounds__(256) void cvt_f32_to_bf16(const float* __restrict__ in,
                                                       ushort* __restrict__ out) {
  long i = ((long)blockIdx.x * 256 + threadIdx.x) * 8;
  float4 a = *(const float4*)(in + i);
  float4 b = *(const float4*)(in + i + 4);
  u16x8 o;
  o[0] = f2b(a.x); o[1] = f2b(a.y); o[2] = f2b(a.z); o[3] = f2b(a.w);
  o[4] = f2b(b.x); o[5] = f2b(b.y); o[6] = f2b(b.z); o[7] = f2b(b.w);
  *(u16x8*)(out + i) = o;
}

// ---------------- RoPE in-place on q,k halves of qkv, vectorized x4 -------
// thread handles 4 consecutive d in [0,32) and their +32 partners.
__global__ __launch_bounds__(256) void rope_kernel(ushort* __restrict__ qkv,
                                                   const float* __restrict__ cosT,
                                                   const float* __restrict__ sinT) {
  long idx = (long)blockIdx.x * 256 + threadIdx.x;  // 2,097,152 total
  int d4 = (int)(idx & 7) * 4;
  int h = (int)((idx >> 3) & 15);
  int which = (int)((idx >> 7) & 1);
  long row = idx >> 8;          // 0..8191
  int s = (int)(row & 2047);
  long base = row * 3072 + which * 1024 + h * 64 + d4;
  ushort4 lo = *(ushort4*)(qkv + base);
  ushort4 hi = *(ushort4*)(qkv + base + 32);
  float4 c0 = *(const float4*)(cosT + s * 64 + d4);
  float4 c1 = *(const float4*)(cosT + s * 64 + d4 + 32);
  float4 s0 = *(const float4*)(sinT + s * 64 + d4);
  float4 s1 = *(const float4*)(sinT + s * 64 + d4 + 32);
  float l0 = b2f(lo.x), l1 = b2f(lo.y), l2 = b2f(lo.z), l3 = b2f(lo.w);
  float h0 = b2f(hi.x), h1 = b2f(hi.y), h2 = b2f(hi.z), h3 = b2f(hi.w);
  ushort4 olo, ohi;
  olo.x = f2b(l0 * c0.x - h0 * s0.x); ohi.x = f2b(h0 * c1.x + l0 * s1.x);
  olo.y = f2b(l1 * c0.y - h1 * s0.y); ohi.y = f2b(h1 * c1.y + l1 * s1.y);
  olo.z = f2b(l2 * c0.z - h2 * s0.z); ohi.z = f2b(h2 * c1.z + l2 * s1.z);
  olo.w = f2b(l3 * c0.w - h3 * s0.w); ohi.w = f2b(h3 * c1.w + l3 * s1.w);
  *(ushort4*)(qkv + base) = olo;
  *(ushort4*)(qkv + base + 32) = ohi;
}

// ---------------- bf16 GEMM: C[M][N] = A[M][K] * B[N][K]^T ----------------
__device__ __forceinline__ void storeC(float* p, float v) { *p = v; }
__device__ __forceinline__ void storeC(bf16* p, float v) { *p = __float2bfloat16(v); }

template <typename CT>
__global__ __launch_bounds__(256) void gemm_bt(const bf16* __restrict__ A,
                                               const bf16* __restrict__ B,
                                               CT* __restrict__ C,
                                               int M, int N, int K) {
  __shared__ bf16 As[128 * 64];
  __shared__ bf16 Bs[128 * 64];
  const int tid = threadIdx.x;
  const int lane = tid & 63;
  const int wid = tid >> 6;
  const int tm = blockIdx.y * 128;
  const int tn = blockIdx.x * 128;
  const int wr = wid >> 1, wc = wid & 1;
  const int srow = tid >> 3;
  const int scol = (tid & 7) * 8;

  f32x4 acc[4][4] = {};

  const bf16* Abase = A + (long)(tm + srow) * K + scol;
  const bf16* Bbase = B + (long)(tn + srow) * K + scol;

  const int lr = lane & 15;
  const int lk = (lane >> 4) * 8;

  for (int k0 = 0; k0 < K; k0 += 64) {
#pragma unroll
    for (int i = 0; i < 4; ++i) {
      async_copy16(Abase + (long)i * 32 * K + k0, (char*)As + wid * 1024 + i * 4096);
      async_copy16(Bbase + (long)i * 32 * K + k0, (char*)Bs + wid * 1024 + i * 4096);
    }
    __syncthreads();
#pragma unroll
    for (int ks = 0; ks < 2; ++ks) {
      s16x8 af[4], bff[4];
#pragma unroll
      for (int m = 0; m < 4; ++m)
        af[m] = *(const s16x8*)&As[(wr * 64 + m * 16 + lr) * 64 + ks * 32 + lk];
#pragma unroll
      for (int n = 0; n < 4; ++n)
        bff[n] = *(const s16x8*)&Bs[(wc * 64 + n * 16 + lr) * 64 + ks * 32 + lk];
#pragma unroll
      for (int m = 0; m < 4; ++m)
#pragma unroll
        for (int n = 0; n < 4; ++n)
          acc[m][n] = __builtin_amdgcn_mfma_f32_16x16x32_bf16(af[m], bff[n], acc[m][n], 0, 0, 0);
    }
    __syncthreads();
  }

  const int cc = lane & 15;
  const int cr = (lane >> 4) * 4;
#pragma unroll
  for (int m = 0; m < 4; ++m)
#pragma unroll
    for (int n = 0; n < 4; ++n) {
      long row0 = tm + wr * 64 + m * 16 + cr;
      long col = tn + wc * 64 + n * 16 + cc;
#pragma unroll
      for (int r = 0; r < 4; ++r)
        storeC(&C[(row0 + r) * (long)N + col], acc[m][n][r]);
    }
}

// ---------------- flash attention, swapped-QK^T softmax ----------------
// grid: (16 q-tiles, 64 (b,h)), 256 threads = 4 waves, 32 q-rows/wave.
// QK^T computed as mfma(K,Q): lane holds S[q=lane&15 (+16*m)][16 keys].
__global__ __launch_bounds__(256, 4) void attn_kernel(const bf16* __restrict__ qkv,
                                                      ushort* __restrict__ o) {
  const int pair = blockIdx.y;
  const int b = pair >> 4, h = pair & 15;
  const int q0 = blockIdx.x * 128;
  const int tid = threadIdx.x, lane = tid & 63, wid = tid >> 6;

  const bf16* Qb = qkv + (long)b * 2048 * 3072 + h * 64;
  const bf16* Kb = Qb + 1024;
  const bf16* Vb = Qb + 2048;

  __shared__ bf16 Ks[64 * 64];
  __shared__ bf16 Vt[64 * 64];
  __shared__ ushort Ps[4][32 * 72];   // [wave][qrow][key], stride 72 ushorts (144B, 16B-aligned rows)

  const int lr = lane & 15;
  const int g = lane >> 4;
  const int lk = g * 8;

  // Q fragments (B operand of swapped QK^T), once per block
  s16x8 qa[2][2];
#pragma unroll
  for (int m = 0; m < 2; ++m)
#pragma unroll
    for (int ks = 0; ks < 2; ++ks)
      qa[m][ks] = *(const s16x8*)(Qb + (long)(q0 + wid * 32 + m * 16 + lr) * 3072 + ks * 32 + lk);

  f32x4 oacc[2][4] = {};            // [qfrag][dfrag], row=qlocal(g*4+r), col=d(lr)
  float mrow[2] = {-1e30f, -1e30f}; // running max (exp2-domain), q = m*16+lr
  float lrow[2] = {0.f, 0.f};

  const float c = 0.125f * 1.44269504f;  // scale * log2(e)

  for (int kt = 0; kt < 32; ++kt) {
    __syncthreads();
    // stage K tile [64 keys][64 d], XOR-swizzled SOURCE (T2 via m173)
#pragma unroll
    for (int i = 0; i < 2; ++i) {
      int cidx = tid + i * 256;
      int row = cidx >> 3;
      int colb = (cidx & 7) * 16;
      int scolb = colb ^ ((row & 7) << 4);
      async_copy16(Kb + (long)(kt * 64 + row) * 3072 + (scolb >> 1),
                   (char*)Ks + wid * 1024 + i * 4096);
    }
    // stage V transposed (Vt[d][key]) + XOR swizzle, via registers
#pragma unroll
    for (int i = 0; i < 4; ++i) {
      int s0 = wid * 4 + i * 16;
      const bf16* vg = Vb + (long)(kt * 64 + s0) * 3072 + lane;
      ushort4 vv;
      vv.x = *(const ushort*)(vg);
      vv.y = *(const ushort*)(vg + 3072);
      vv.z = *(const ushort*)(vg + 2 * 3072);
      vv.w = *(const ushort*)(vg + 3 * 3072);
      int byte = lane * 128 + ((s0 * 2) ^ ((lane & 7) << 4));
      *(ushort4*)((char*)Vt + byte) = vv;
    }
    __syncthreads();

    // S^T = K Q^T : sacc[n][m], row = key_local(g*4+r), col = q_local(lr)
    f32x4 sacc[4][2] = {};
    __builtin_amdgcn_s_setprio(1);
#pragma unroll
    for (int ks = 0; ks < 2; ++ks) {
      s16x8 kf[4];
#pragma unroll
      for (int n = 0; n < 4; ++n) {
        int row = n * 16 + lr;
        int colb = (ks * 32 + lk) * 2;
        kf[n] = *(const s16x8*)((const char*)Ks + row * 128 + (colb ^ ((row & 7) << 4)));
      }
#pragma unroll
      for (int n = 0; n < 4; ++n)
#pragma unroll
        for (int m = 0; m < 2; ++m)
          sacc[n][m] = __builtin_amdgcn_mfma_f32_16x16x32_bf16(kf[n], qa[m][ks], sacc[n][m], 0, 0, 0);
    }
    __builtin_amdgcn_s_setprio(0);

    // ---- softmax: lane owns q = m*16+lr, 16 keys at n*16 + g*4 + r ----
    float vmax[2];
#pragma unroll
    for (int m = 0; m < 2; ++m) {
      float t = -1e30f;
#pragma unroll
      for (int n = 0; n < 4; ++n)
#pragma unroll
        for (int r = 0; r < 4; ++r) {
          sacc[n][m][r] *= c;
          t = fmaxf(t, sacc[n][m][r]);
        }
      t = fmaxf(t, __shfl_xor(t, 16, 64));
      t = fmaxf(t, __shfl_xor(t, 32, 64));
      vmax[m] = t;
    }
    // T13 defer-max: only rescale when the max actually grew past THR
    bool need = !__all((vmax[0] <= mrow[0] + 8.f) && (vmax[1] <= mrow[1] + 8.f));
    if (need) {
#pragma unroll
      for (int m = 0; m < 2; ++m) {
        float mnew = fmaxf(mrow[m], vmax[m]);
        float al = exp2f(mrow[m] - mnew);
        mrow[m] = mnew;
        lrow[m] *= al;
#pragma unroll
        for (int r = 0; r < 4; ++r) {
          float a = __shfl(al, ((lane >> 4) << 2) + r, 64);
#pragma unroll
          for (int n2 = 0; n2 < 4; ++n2) oacc[m][n2][r] *= a;
        }
      }
    }
    // p = exp2(v - m), accumulate l, pack to bf16, vector-store rows of Ps
#pragma unroll
    for (int m = 0; m < 2; ++m) {
      float ps = 0.f;
      ushort* prow = &Ps[wid][(m * 16 + lr) * 72 + g * 4];
#pragma unroll
      for (int n = 0; n < 4; ++n) {
        float p0 = exp2f(sacc[n][m][0] - mrow[m]);
        float p1 = exp2f(sacc[n][m][1] - mrow[m]);
        float p2 = exp2f(sacc[n][m][2] - mrow[m]);
        float p3 = exp2f(sacc[n][m][3] - mrow[m]);
        ps += (p0 + p1) + (p2 + p3);
        ushort4 w;
        w.x = f2b(p0); w.y = f2b(p1); w.z = f2b(p2); w.w = f2b(p3);
        *(ushort4*)(prow + n * 16) = w;
      }
      ps += __shfl_xor(ps, 16, 64);
      ps += __shfl_xor(ps, 32, 64);
      lrow[m] += ps;
    }

    // O += P V : mfma(A=P rows q, B=Vt rows d) -> row=qlocal, col=d
    __builtin_amdgcn_s_setprio(1);
#pragma unroll
    for (int ks = 0; ks < 2; ++ks) {
      s16x8 pa[2], vf[4];
#pragma unroll
      for (int m = 0; m < 2; ++m)
        pa[m] = *(const s16x8*)&Ps[wid][(m * 16 + lr) * 72 + ks * 32 + lk];
#pragma unroll
      for (int n = 0; n < 4; ++n) {
        int row = n * 16 + lr;
        int colb = (ks * 32 + lk) * 2;
        vf[n] = *(const s16x8*)((const char*)Vt + row * 128 + (colb ^ ((row & 7) << 4)));
      }
#pragma unroll
      for (int m = 0; m < 2; ++m)
#pragma unroll
        for (int n = 0; n < 4; ++n)
          oacc[m][n] = __builtin_amdgcn_mfma_f32_16x16x32_bf16(pa[m], vf[n], oacc[m][n], 0, 0, 0);
    }
    __builtin_amdgcn_s_setprio(0);
  }

  // epilogue: O/l -> o[b*2048+s][h*64+d] (bf16); lrow lives at lane lr==qlocal
#pragma unroll
  for (int m = 0; m < 2; ++m)
#pragma unroll
    for (int r = 0; r < 4; ++r) {
      float inv = 1.f / __shfl(lrow[m], ((lane >> 4) << 2) + r, 64);
      int rl = g * 4 + r;
      long srow = q0 + wid * 32 + m * 16 + rl;
#pragma unroll
      for (int n = 0; n < 4; ++n) {
        int d = n * 16 + lr;
        o[((long)b * 2048 + srow) * 1024 + h * 64 + d] = f2b(oacc[m][n][r] * inv);
      }
    }
}

// ---------------- launch ----------------
extern "C" void kernel_launch(void* const* d_in, const int* in_sizes, int n_in,
                              void* d_out, int out_size, void* d_ws, size_t ws_size,
                              hipStream_t stream) {
  const float* x    = (const float*)d_in[0];
  const float* cosT = (const float*)d_in[1];
  const float* sinT = (const float*)d_in[2];
  const float* Wqkv = (const float*)d_in[3];
  const float* Wout = (const float*)d_in[4];
  float* out = (float*)d_out;

  char* p = (char*)d_ws;
  bf16* xb    = (bf16*)p; p += (size_t)8192 * 1024 * 2;
  bf16* wqkvb = (bf16*)p; p += (size_t)3072 * 1024 * 2;
  bf16* woutb = (bf16*)p; p += (size_t)1024 * 1024 * 2;
  bf16* qkvb  = (bf16*)p; p += (size_t)8192 * 3072 * 2;
  bf16* ob    = (bf16*)p;

  cvt_f32_to_bf16<<<4096, 256, 0, stream>>>(x, (ushort*)xb);
  cvt_f32_to_bf16<<<1536, 256, 0, stream>>>(Wqkv, (ushort*)wqkvb);
  cvt_f32_to_bf16<<<512, 256, 0, stream>>>(Wout, (ushort*)woutb);

  // qkv = x @ Wqkv^T : M=8192, N=3072, K=1024
  gemm_bt<bf16><<<dim3(24, 64), 256, 0, stream>>>(xb, wqkvb, qkvb, 8192, 3072, 1024);

  rope_kernel<<<8192, 256, 0, stream>>>((ushort*)qkvb, cosT, sinT);

  attn_kernel<<<dim3(16, 64), 256, 0, stream>>>(qkvb, (ushort*)ob);

  // out = o @ Wout^T : M=8192, N=1024, K=1024 (fp32 out)
  gemm_bt<float><<<dim3(8, 64), 256, 0, stream>>>(ob, woutb, out, 8192, 1024, 1024);
}